// Round 19
// baseline (116.160 us; speedup 1.0000x reference)
//
#include <hip/hip_runtime.h>
#include <hip/hip_bf16.h>

#define NB 32
#define NT 1024
#define ND 256
#define SP 264      // LDS tile pitch (bf16 elems): 528B rows, 16B-aligned
#define ETA 0.1f
#define INVS 0.70710678118654752440f

typedef short bf16x8 __attribute__((ext_vector_type(8)));
typedef float f32x4  __attribute__((ext_vector_type(4)));

__device__ inline unsigned short f2bf(float f){
  __hip_bfloat16 h = __float2bfloat16(f);
  return *reinterpret_cast<unsigned short*>(&h);
}
__device__ inline float bf2f(unsigned short u){
  return __uint_as_float(((unsigned int)u) << 16);
}

// ---- scalar Haar ladders (compile-time indices) ----
template<int N>
__device__ inline void idwtT(float* a, const float* d){
#pragma unroll
  for (int i = N-1; i >= 0; --i){
    float av = a[i], dv = d[i];
    a[2*i]   = (av + dv) * INVS;
    a[2*i+1] = (av - dv) * INVS;
  }
}
template<int N>
__device__ inline void dwtT(float* a, float* d){
#pragma unroll
  for (int i = 0; i < N; ++i){
    float e = a[2*i], o = a[2*i+1];
    a[i] = (e + o) * INVS;
    d[i] = (e - o) * INVS;
  }
}
// coarse DWT level with shared path-detail + dual own-row extraction
template<int N>
__device__ inline void dwt_sel2(float* x, int pj, float& pdet,
                                int j0, float& y0, int j1, float& y1){
#pragma unroll
  for (int i = 0; i < N; ++i){
    float e = x[2*i], o = x[2*i+1];
    float aa = (e + o) * INVS, dd = (e - o) * INVS;
    x[i] = aa;
    if (i == pj)    pdet = dd;
    if (N + i == j0) y0 = dd;
    if (N + i == j1) y1 = dd;
  }
}
// single-extraction variant (k_fin2)
template<int N>
__device__ inline void dwt_sel(float* x, int j, float& yj){
#pragma unroll
  for (int i = 0; i < N; ++i){
    float e = x[2*i], o = x[2*i+1];
    float aa = (e + o) * INVS, dd = (e - o) * INVS;
    x[i] = aa;
    if (N + i == j) yj = dd;
  }
}

__device__ inline void fine_rows(int j, int* fr){
  fr[0] = 64 + j;
#pragma unroll
  for (int i = 0; i < 2; ++i) fr[1+i] = 128 + 2*j + i;
#pragma unroll
  for (int i = 0; i < 4; ++i) fr[3+i] = 256 + 4*j + i;
#pragma unroll
  for (int i = 0; i < 8; ++i) fr[7+i] = 512 + 8*j + i;
}

// ---- GEMM accumulate: one wave, M32 x N64 for `band`, A from lds; acc in regs ----
__device__ inline void gemm_acc(const unsigned short* lds,
                                const unsigned short* __restrict__ Wt,
                                int band, int n0, int row16, int kg,
                                f32x4 acc[2][4]){
  const unsigned short* Wb = Wt + (size_t)band * 65536;
#pragma unroll
  for (int mi = 0; mi < 2; ++mi)
#pragma unroll
    for (int ni = 0; ni < 4; ++ni) acc[mi][ni] = (f32x4){0.f,0.f,0.f,0.f};
#pragma unroll
  for (int kk = 0; kk < 8; ++kk){
    bf16x8 a0 = *(const bf16x8*)&lds[row16*SP + kk*32 + kg*8];
    bf16x8 a1 = *(const bf16x8*)&lds[(16 + row16)*SP + kk*32 + kg*8];
#pragma unroll
    for (int ni = 0; ni < 4; ++ni){
      bf16x8 bw = *(const bf16x8*)(Wb + (size_t)(n0 + 16*ni + row16)*256 + kk*32 + kg*8);
      acc[0][ni] = __builtin_amdgcn_mfma_f32_16x16x32_bf16(a0, bw, acc[0][ni], 0,0,0);
      acc[1][ni] = __builtin_amdgcn_mfma_f32_16x16x32_bf16(a1, bw, acc[1][ni], 0,0,0);
    }
  }
}

// ---- GEMM phase: compute fin[2][4] (bias added) in registers ----
__device__ inline void gemm_phase(const unsigned short* lds,
                                  const unsigned short* __restrict__ Wt,
                                  const float* __restrict__ bias,
                                  int p, int n0, int row16, int kg,
                                  f32x4 fin[2][4]){
  if (p > 0){
    int band = 32 - __clz(32*p);
    f32x4 acc[2][4];
    gemm_acc(lds, Wt, band, n0, row16, kg, acc);
    float bv[4];
#pragma unroll
    for (int ni = 0; ni < 4; ++ni) bv[ni] = bias[band*256 + n0 + 16*ni + row16];
#pragma unroll
    for (int mi = 0; mi < 2; ++mi)
#pragma unroll
      for (int ni = 0; ni < 4; ++ni)
#pragma unroll
        for (int jj = 0; jj < 4; ++jj)
          fin[mi][ni][jj] = acc[mi][ni][jj] + bv[ni];
  } else {
#pragma unroll
    for (int bd = 0; bd < 6; ++bd){
      int lo = (bd==0) ? 0 : (1<<(bd-1));
      int hi = (bd==0) ? 1 : (1<<bd);
      f32x4 acc[2][4];
      gemm_acc(lds, Wt, bd, n0, row16, kg, acc);
      float bv[4];
#pragma unroll
      for (int ni = 0; ni < 4; ++ni) bv[ni] = bias[bd*256 + n0 + 16*ni + row16];
#pragma unroll
      for (int mi = 0; mi < 2; ++mi)
#pragma unroll
        for (int ni = 0; ni < 4; ++ni)
#pragma unroll
          for (int jj = 0; jj < 4; ++jj){
            int trow = 16*mi + kg*4 + jj;
            if (trow >= lo && trow < hi)
              fin[mi][ni][jj] = acc[mi][ni][jj] + bv[ni];
          }
    }
  }
}

// ================ BIG1: IDWT(w*rho) -> GEMM -> fine DWT + blend -> cf16, st1 ================
__global__ __launch_bounds__(256, 2) void k_big1(const float* __restrict__ rho,
                                                 const float* __restrict__ w,
                                                 const unsigned short* __restrict__ Wt,
                                                 const float* __restrict__ bias,
                                                 unsigned short* __restrict__ cf16,
                                                 float* __restrict__ st1){
  __shared__ __align__(16) unsigned short lds[32*SP];
  int bx = blockIdx.x;
  int b = bx & 31, p = bx >> 5;        // p=0: masked rows 0..31; p>=1: rows 32p..32p+31
  int col = threadIdx.x;
  size_t cb = (size_t)b*NT*ND;

  float cva[2][15];                    // held w*rho fine-row products
  // ---------- phase A: per-chunk IDWT -> lds (S tile) ----------
  {
    int crow[7]; crow[0] = 0;
#pragma unroll
    for (int l = 6; l >= 1; --l) crow[7-l] = (64>>l) + ((2*p) >> l);
    float cpr[7];
#pragma unroll
    for (int i = 0; i < 7; ++i)
      cpr[i] = rho[cb + (size_t)crow[i]*ND + col] * w[(size_t)crow[i]*ND + col];
    float apre = cpr[0];
#pragma unroll
    for (int l = 6; l >= 2; --l){
      float s = (((2*p) >> (l-1)) & 1) ? -INVS : INVS;
      apre = apre*INVS + cpr[7-l]*s;
    }
#pragma unroll
    for (int jj = 0; jj < 2; ++jj){
      int j = 2*p + jj;
      float a = apre*INVS + cpr[6]*(jj ? -INVS : INVS);
      int fr[15]; fine_rows(j, fr);
      float f4, f3[2], f2a[4], f1[8];
      {
        float fv[15];
#pragma unroll
        for (int i = 0; i < 15; ++i){
          fv[i] = rho[cb + (size_t)fr[i]*ND + col] * w[(size_t)fr[i]*ND + col];
          cva[jj][i] = fv[i];
        }
        f4 = fv[0];
#pragma unroll
        for (int i = 0; i < 2; ++i) f3[i]  = fv[1+i];
#pragma unroll
        for (int i = 0; i < 4; ++i) f2a[i] = fv[3+i];
#pragma unroll
        for (int i = 0; i < 8; ++i) f1[i]  = fv[7+i];
      }
      float A[16]; A[0] = a;
      idwtT<1>(A, &f4); idwtT<2>(A, f3); idwtT<4>(A, f2a); idwtT<8>(A, f1);
#pragma unroll
      for (int i = 0; i < 16; ++i) lds[(16*jj + i)*SP + col] = f2bf(A[i]);
    }
  }
  __syncthreads();
  // ---------- phase B: GEMM into registers ----------
  f32x4 fin[2][4];
  {
    int wv = threadIdx.x >> 6, lane = threadIdx.x & 63;
    int row16 = lane & 15, kg = lane >> 4, n0 = wv*64;
    gemm_phase(lds, Wt, bias, p, n0, row16, kg, fin);
  }
  __syncthreads();                     // all S reads done
  {
    int wv = threadIdx.x >> 6, lane = threadIdx.x & 63;
    int row16 = lane & 15, kg = lane >> 4, n0 = wv*64;
#pragma unroll
    for (int ni = 0; ni < 4; ++ni)
#pragma unroll
      for (int mi = 0; mi < 2; ++mi)
#pragma unroll
        for (int jj = 0; jj < 4; ++jj){
          int trow = 16*mi + kg*4 + jj;
          lds[trow*SP + n0 + 16*ni + row16] = f2bf(fin[mi][ni][jj]);
        }
  }
  __syncthreads();
  // ---------- phase C: fine DWT of Y-tile, blend with held cva, write cf16 + st1 ----------
#pragma unroll
  for (int jj = 0; jj < 2; ++jj){
    int j = 2*p + jj;
    float x[16];
#pragma unroll
    for (int i = 0; i < 16; ++i) x[i] = bf2f(lds[(16*jj + i)*SP + col]);
    float d1[8], d2v[4], d3[2], d4v;
    dwtT<8>(x, d1); dwtT<4>(x, d2v); dwtT<2>(x, d3); dwtT<1>(x, &d4v);
    st1[((size_t)b*64 + j)*ND + col] = x[0];
    int fr[15]; fine_rows(j, fr);
    float det[15];
    det[0] = d4v;
#pragma unroll
    for (int i = 0; i < 2; ++i) det[1+i] = d3[i];
#pragma unroll
    for (int i = 0; i < 4; ++i) det[3+i] = d2v[i];
#pragma unroll
    for (int i = 0; i < 8; ++i) det[7+i] = d1[i];
#pragma unroll
    for (int i = 0; i < 15; ++i){
      float cv = cva[jj][i];
      cf16[cb + (size_t)fr[i]*ND + col] = f2bf(cv - ETA*(cv - det[i]));
    }
  }
}

// ============ BIG2: coarse walk + IDWT(c') -> GEMM -> final DWT/blend/div -> c, st2 ============
__global__ __launch_bounds__(256, 2) void k_big2(const float* __restrict__ st1,
                                                 const float* __restrict__ rho,
                                                 const float* __restrict__ w,
                                                 const unsigned short* __restrict__ cf16,
                                                 const unsigned short* __restrict__ Wt,
                                                 const float* __restrict__ bias,
                                                 float* __restrict__ c,
                                                 float* __restrict__ st2){
  __shared__ __align__(16) unsigned short lds[32*SP];
  int bx = blockIdx.x;
  int b = bx & 31, p = bx >> 5;
  int col = threadIdx.x;
  size_t cb = (size_t)b*NT*ND;
  int j0 = 2*p, j1 = 2*p + 1;

  float cfa[2][15];                    // held c' fine-row values (bf16-decoded)
  // ---------- phase A: one stash walk (dual extraction) + leaf blends + fine IDWT -> lds ----------
  {
    float x[64];
#pragma unroll
    for (int k = 0; k < 64; ++k) x[k] = st1[((size_t)b*64 + k)*ND + col];
    float pd[6], y0 = 0.f, y1 = 0.f;
    dwt_sel2<32>(x, j0>>1, pd[0], j0, y0, j1, y1);
    dwt_sel2<16>(x, j0>>2, pd[1], j0, y0, j1, y1);
    dwt_sel2< 8>(x, j0>>3, pd[2], j0, y0, j1, y1);
    dwt_sel2< 4>(x, j0>>4, pd[3], j0, y0, j1, y1);
    dwt_sel2< 2>(x, j0>>5, pd[4], j0, y0, j1, y1);
    dwt_sel2< 1>(x, j0>>6, pd[5], j0, y0, j1, y1);
    if (j0 == 0) y0 = x[0];

    float cpr[7];
    cpr[0] = rho[cb + col] * w[col];
#pragma unroll
    for (int l = 6; l >= 1; --l){
      int r = (64>>l) + (j0>>l);
      cpr[7-l] = rho[cb + (size_t)r*ND + col] * w[(size_t)r*ND + col];
    }
    {
      float cv = rho[cb + (size_t)j0*ND + col] * w[(size_t)j0*ND + col];
      c[cb + (size_t)j0*ND + col] = cv - ETA*(cv - y0);
      float cw = rho[cb + (size_t)j1*ND + col] * w[(size_t)j1*ND + col];
      c[cb + (size_t)j1*ND + col] = cw - ETA*(cw - y1);
    }
    float ncl[6];
#pragma unroll
    for (int l = 1; l <= 6; ++l){
      float cv = cpr[7-l];
      ncl[l-1] = cv - ETA*(cv - pd[l-1]);
    }
    float cvr = cpr[0];
    float apre = cvr - ETA*(cvr - x[0]);
#pragma unroll
    for (int l = 6; l >= 2; --l){
      float s = ((j0 >> (l-1)) & 1) ? -1.f : 1.f;
      apre = (apre + s*ncl[l-1]) * INVS;
    }
#pragma unroll
    for (int jj = 0; jj < 2; ++jj){
      int j = j0 + jj;
      float a = (apre + (jj ? -1.f : 1.f)*ncl[0]) * INVS;
      int fr[15]; fine_rows(j, fr);
      float f4, f3[2], f2a[4], f1[8];
      {
        float fv[15];
#pragma unroll
        for (int i = 0; i < 15; ++i){
          fv[i] = bf2f(cf16[cb + (size_t)fr[i]*ND + col]);
          cfa[jj][i] = fv[i];
        }
        f4 = fv[0];
#pragma unroll
        for (int i = 0; i < 2; ++i) f3[i]  = fv[1+i];
#pragma unroll
        for (int i = 0; i < 4; ++i) f2a[i] = fv[3+i];
#pragma unroll
        for (int i = 0; i < 8; ++i) f1[i]  = fv[7+i];
      }
      float A[16]; A[0] = a;
      idwtT<1>(A, &f4); idwtT<2>(A, f3); idwtT<4>(A, f2a); idwtT<8>(A, f1);
#pragma unroll
      for (int i = 0; i < 16; ++i) lds[(16*jj + i)*SP + col] = f2bf(A[i]);
    }
  }
  __syncthreads();
  // ---------- phase B: GEMM into registers ----------
  f32x4 fin[2][4];
  {
    int wv = threadIdx.x >> 6, lane = threadIdx.x & 63;
    int row16 = lane & 15, kg = lane >> 4, n0 = wv*64;
    gemm_phase(lds, Wt, bias, p, n0, row16, kg, fin);
  }
  __syncthreads();
  {
    int wv = threadIdx.x >> 6, lane = threadIdx.x & 63;
    int row16 = lane & 15, kg = lane >> 4, n0 = wv*64;
#pragma unroll
    for (int ni = 0; ni < 4; ++ni)
#pragma unroll
      for (int mi = 0; mi < 2; ++mi)
#pragma unroll
        for (int jj = 0; jj < 4; ++jj){
          int trow = 16*mi + kg*4 + jj;
          lds[trow*SP + n0 + 16*ni + row16] = f2bf(fin[mi][ni][jj]);
        }
  }
  __syncthreads();
  // ---------- phase C: final fine DWT, blend with held cfa, divide by w -> out; stash2 ----------
#pragma unroll
  for (int jj = 0; jj < 2; ++jj){
    int j = j0 + jj;
    float x[16];
#pragma unroll
    for (int i = 0; i < 16; ++i) x[i] = bf2f(lds[(16*jj + i)*SP + col]);
    float d1[8], d2v[4], d3[2], d4v;
    dwtT<8>(x, d1); dwtT<4>(x, d2v); dwtT<2>(x, d3); dwtT<1>(x, &d4v);
    st2[((size_t)b*64 + j)*ND + col] = x[0];
    int fr[15]; fine_rows(j, fr);
    float det[15];
    det[0] = d4v;
#pragma unroll
    for (int i = 0; i < 2; ++i) det[1+i] = d3[i];
#pragma unroll
    for (int i = 0; i < 4; ++i) det[3+i] = d2v[i];
#pragma unroll
    for (int i = 0; i < 8; ++i) det[7+i] = d1[i];
#pragma unroll
    for (int i = 0; i < 15; ++i){
      float cv = cfa[jj][i];
      float ww = w[(size_t)fr[i]*ND + col];
      c[cb + (size_t)fr[i]*ND + col] = (cv - ETA*(cv - det[i])) / ww;
    }
  }
}

// ---------------- k_fin2: out coarse row j from stash2 ----------------
__global__ __launch_bounds__(256, 4) void k_fin2(const float* __restrict__ st2,
                                                 const float* __restrict__ w,
                                                 float* __restrict__ c){
  int b = blockIdx.y, j = blockIdx.x, d = threadIdx.x;
  size_t cb = (size_t)b*NT*ND;

  float x[64];
#pragma unroll
  for (int k = 0; k < 64; ++k) x[k] = st2[((size_t)b*64 + k)*ND + d];

  float cj = c[cb + (size_t)j*ND + d];       // c' coarse row j (from k_big2)
  float wj = w[(size_t)j*ND + d];

  float yj = 0.f;
  dwt_sel<32>(x, j, yj);
  dwt_sel<16>(x, j, yj);
  dwt_sel< 8>(x, j, yj);
  dwt_sel< 4>(x, j, yj);
  dwt_sel< 2>(x, j, yj);
  dwt_sel< 1>(x, j, yj);
  if (j == 0) yj = x[0];

  c[cb + (size_t)j*ND + d] = (cj - ETA*(cj - yj)) / wj;
}

// ---------------- Wt[band][e][d] = bf16(W[band][d][e]) ----------------
__global__ __launch_bounds__(256) void k_wprep(const float* __restrict__ W,
                                               unsigned short* __restrict__ Wt){
  __shared__ float tbuf[32][33];
  int band = blockIdx.y;
  int tile = blockIdx.x;             // 0..63 -> 8x8 grid of 32x32 tiles
  int td0 = (tile >> 3) * 32, te0 = (tile & 7) * 32;
  int tx = threadIdx.x & 31, ty = threadIdx.x >> 5;
#pragma unroll
  for (int i = 0; i < 4; ++i){
    tbuf[ty*4 + i][tx] = W[(size_t)band*65536 + (size_t)(td0 + ty*4 + i)*256 + te0 + tx];
  }
  __syncthreads();
#pragma unroll
  for (int i = 0; i < 4; ++i){
    Wt[(size_t)band*65536 + (size_t)(te0 + ty*4 + i)*256 + td0 + tx] = f2bf(tbuf[tx][ty*4 + i]);
  }
}

extern "C" void kernel_launch(void* const* d_in, const int* in_sizes, int n_in,
                              void* d_out, int out_size, void* d_ws, size_t ws_size,
                              hipStream_t stream){
  const float* rho  = (const float*)d_in[0];
  const float* w    = (const float*)d_in[1];
  const float* W    = (const float*)d_in[2];
  const float* bias = (const float*)d_in[3];

  float* c = (float*)d_out;                                   // output buffer
  unsigned short* Wt = (unsigned short*)d_ws;                 // 1.44 MB bf16 transposed weights
  float* st1 = (float*)(Wt + (size_t)11 * 65536);             // 2 MB [b][64][256]
  float* st2 = st1 + (size_t)NB * 64 * ND;                    // 2 MB [b][64][256]
  unsigned short* cf16 = (unsigned short*)(st2 + (size_t)NB * 64 * ND);  // 16.8 MB bf16 c' fine rows

  k_wprep<<<dim3(64, 11), 256, 0, stream>>>(W, Wt);
  k_big1<<<NB*32, 256, 0, stream>>>(rho, w, Wt, bias, cf16, st1);
  k_big2<<<NB*32, 256, 0, stream>>>(st1, rho, w, cf16, Wt, bias, c, st2);
  k_fin2<<<dim3(64, NB), 256, 0, stream>>>(st2, w, c);
}

// Round 20
// 96.639 us; speedup vs baseline: 1.2020x; 1.2020x over previous
//
#include <hip/hip_runtime.h>
#include <hip/hip_bf16.h>

#define NB 32
#define NT 1024
#define ND 256
#define SP 264      // LDS tile pitch (bf16 elems): 528B rows, 16B-aligned
#define ETA 0.1f
#define INVS 0.70710678118654752440f

typedef short bf16x8 __attribute__((ext_vector_type(8)));
typedef float f32x4  __attribute__((ext_vector_type(4)));

__device__ inline unsigned short f2bf(float f){
  __hip_bfloat16 h = __float2bfloat16(f);
  return *reinterpret_cast<unsigned short*>(&h);
}
__device__ inline float bf2f(unsigned short u){
  return __uint_as_float(((unsigned int)u) << 16);
}

// ---- scalar Haar ladders (compile-time indices) ----
template<int N>
__device__ inline void idwtT(float* a, const float* d){
#pragma unroll
  for (int i = N-1; i >= 0; --i){
    float av = a[i], dv = d[i];
    a[2*i]   = (av + dv) * INVS;
    a[2*i+1] = (av - dv) * INVS;
  }
}
template<int N>
__device__ inline void dwtT(float* a, float* d){
#pragma unroll
  for (int i = 0; i < N; ++i){
    float e = a[2*i], o = a[2*i+1];
    a[i] = (e + o) * INVS;
    d[i] = (e - o) * INVS;
  }
}
// coarse DWT level with shared path-detail + dual own-row extraction
template<int N>
__device__ inline void dwt_sel2(float* x, int pj, float& pdet,
                                int j0, float& y0, int j1, float& y1){
#pragma unroll
  for (int i = 0; i < N; ++i){
    float e = x[2*i], o = x[2*i+1];
    float aa = (e + o) * INVS, dd = (e - o) * INVS;
    x[i] = aa;
    if (i == pj)    pdet = dd;
    if (N + i == j0) y0 = dd;
    if (N + i == j1) y1 = dd;
  }
}
// single-extraction variant (k_fin2)
template<int N>
__device__ inline void dwt_sel(float* x, int j, float& yj){
#pragma unroll
  for (int i = 0; i < N; ++i){
    float e = x[2*i], o = x[2*i+1];
    float aa = (e + o) * INVS, dd = (e - o) * INVS;
    x[i] = aa;
    if (N + i == j) yj = dd;
  }
}

__device__ inline void fine_rows(int j, int* fr){
  fr[0] = 64 + j;
#pragma unroll
  for (int i = 0; i < 2; ++i) fr[1+i] = 128 + 2*j + i;
#pragma unroll
  for (int i = 0; i < 4; ++i) fr[3+i] = 256 + 4*j + i;
#pragma unroll
  for (int i = 0; i < 8; ++i) fr[7+i] = 512 + 8*j + i;
}

// ---- GEMM phase: one wave computes M32 x N64 for given band, A from ldsS, Y -> ldsY ----
__device__ inline void gemm_tile_lds(const unsigned short* ldsS,
                                     unsigned short* ldsY,
                                     const unsigned short* __restrict__ Wt,
                                     const float* __restrict__ bias,
                                     int band, int n0, int row16, int kg,
                                     int lo, int hi){
  const unsigned short* Wb = Wt + (size_t)band * 65536;
  bf16x8 breg[8][4];
#pragma unroll
  for (int kk = 0; kk < 8; ++kk)
#pragma unroll
    for (int ni = 0; ni < 4; ++ni)
      breg[kk][ni] = *(const bf16x8*)(Wb + (size_t)(n0 + 16*ni + row16)*256 + kk*32 + kg*8);
  float bv[4];
#pragma unroll
  for (int ni = 0; ni < 4; ++ni) bv[ni] = bias[band*256 + n0 + 16*ni + row16];

  f32x4 acc[2][4];
#pragma unroll
  for (int mi = 0; mi < 2; ++mi)
#pragma unroll
    for (int ni = 0; ni < 4; ++ni) acc[mi][ni] = (f32x4){0.f,0.f,0.f,0.f};

#pragma unroll
  for (int kk = 0; kk < 8; ++kk){
    bf16x8 a0 = *(const bf16x8*)&ldsS[row16*SP + kk*32 + kg*8];
    bf16x8 a1 = *(const bf16x8*)&ldsS[(16 + row16)*SP + kk*32 + kg*8];
#pragma unroll
    for (int ni = 0; ni < 4; ++ni){
      acc[0][ni] = __builtin_amdgcn_mfma_f32_16x16x32_bf16(a0, breg[kk][ni], acc[0][ni], 0,0,0);
      acc[1][ni] = __builtin_amdgcn_mfma_f32_16x16x32_bf16(a1, breg[kk][ni], acc[1][ni], 0,0,0);
    }
  }
#pragma unroll
  for (int ni = 0; ni < 4; ++ni)
#pragma unroll
    for (int mi = 0; mi < 2; ++mi)
#pragma unroll
      for (int jj = 0; jj < 4; ++jj){
        int trow = 16*mi + kg*4 + jj;   // C/D: row=(lane>>4)*4+reg, col=lane&15
        if (trow >= lo && trow < hi)
          ldsY[trow*SP + n0 + 16*ni + row16] = f2bf(acc[mi][ni][jj] + bv[ni]);
      }
}

// ================ BIG1: IDWT(w*rho) -> GEMM -> fine DWT + blend -> cf16, st1 ================
__global__ __launch_bounds__(256, 2) void k_big1(const float* __restrict__ rho,
                                                 const float* __restrict__ w,
                                                 const unsigned short* __restrict__ Wt,
                                                 const float* __restrict__ bias,
                                                 unsigned short* __restrict__ cf16,
                                                 float* __restrict__ st1){
  __shared__ __align__(16) unsigned short ldsS[32*SP];
  __shared__ __align__(16) unsigned short ldsY[32*SP];
  int bx = blockIdx.x;
  int b = bx & 31, p = bx >> 5;        // p=0: masked rows 0..31; p>=1: rows 32p..32p+31
  int col = threadIdx.x;
  int t0 = 32*p;
  size_t cb = (size_t)b*NT*ND;

  float cva[2][15];                    // held w*rho fine-row products
  // ---------- phase A: per-chunk IDWT -> ldsS ----------
  {
    // shared coarse leaf path (7 rows; j0,j1 share all of them)
    int crow[7]; crow[0] = 0;
#pragma unroll
    for (int l = 6; l >= 1; --l) crow[7-l] = (64>>l) + ((2*p) >> l);
    float cpr[7];
#pragma unroll
    for (int i = 0; i < 7; ++i)
      cpr[i] = rho[cb + (size_t)crow[i]*ND + col] * w[(size_t)crow[i]*ND + col];
    float apre = cpr[0];
#pragma unroll
    for (int l = 6; l >= 2; --l){
      float s = (((2*p) >> (l-1)) & 1) ? -INVS : INVS;
      apre = apre*INVS + cpr[7-l]*s;
    }
#pragma unroll
    for (int jj = 0; jj < 2; ++jj){
      int j = 2*p + jj;
      float a = apre*INVS + cpr[6]*(jj ? -INVS : INVS);
      int fr[15]; fine_rows(j, fr);
      float f4, f3[2], f2a[4], f1[8];
      {
        float fv[15];
#pragma unroll
        for (int i = 0; i < 15; ++i){
          fv[i] = rho[cb + (size_t)fr[i]*ND + col] * w[(size_t)fr[i]*ND + col];
          cva[jj][i] = fv[i];
        }
        f4 = fv[0];
#pragma unroll
        for (int i = 0; i < 2; ++i) f3[i]  = fv[1+i];
#pragma unroll
        for (int i = 0; i < 4; ++i) f2a[i] = fv[3+i];
#pragma unroll
        for (int i = 0; i < 8; ++i) f1[i]  = fv[7+i];
      }
      float A[16]; A[0] = a;
      idwtT<1>(A, &f4); idwtT<2>(A, f3); idwtT<4>(A, f2a); idwtT<8>(A, f1);
#pragma unroll
      for (int i = 0; i < 16; ++i) ldsS[(16*jj + i)*SP + col] = f2bf(A[i]);
    }
  }
  __syncthreads();
  // ---------- phase B: GEMM ----------
  {
    int wv = threadIdx.x >> 6, lane = threadIdx.x & 63;
    int row16 = lane & 15, kg = lane >> 4, n0 = wv*64;
    if (p > 0){
      int band = 32 - __clz(t0);
      gemm_tile_lds(ldsS, ldsY, Wt, bias, band, n0, row16, kg, 0, 32);
    } else {
#pragma unroll
      for (int bd = 0; bd < 6; ++bd){
        int lo = (bd==0) ? 0 : (1<<(bd-1));
        int hi = (bd==0) ? 1 : (1<<bd);
        gemm_tile_lds(ldsS, ldsY, Wt, bias, bd, n0, row16, kg, lo, hi);
      }
    }
  }
  __syncthreads();
  // ---------- phase C: fine DWT of Y-tile, blend with held cva, write cf16 + st1 ----------
#pragma unroll
  for (int jj = 0; jj < 2; ++jj){
    int j = 2*p + jj;
    float x[16];
#pragma unroll
    for (int i = 0; i < 16; ++i) x[i] = bf2f(ldsY[(16*jj + i)*SP + col]);
    float d1[8], d2v[4], d3[2], d4v;
    dwtT<8>(x, d1); dwtT<4>(x, d2v); dwtT<2>(x, d3); dwtT<1>(x, &d4v);
    st1[((size_t)b*64 + j)*ND + col] = x[0];
    int fr[15]; fine_rows(j, fr);
    float det[15];
    det[0] = d4v;
#pragma unroll
    for (int i = 0; i < 2; ++i) det[1+i] = d3[i];
#pragma unroll
    for (int i = 0; i < 4; ++i) det[3+i] = d2v[i];
#pragma unroll
    for (int i = 0; i < 8; ++i) det[7+i] = d1[i];
#pragma unroll
    for (int i = 0; i < 15; ++i){
      float cv = cva[jj][i];
      cf16[cb + (size_t)fr[i]*ND + col] = f2bf(cv - ETA*(cv - det[i]));
    }
  }
}

// ============ BIG2: coarse walk + IDWT(c') -> GEMM -> final DWT/blend/div -> c, st2 ============
__global__ __launch_bounds__(256, 2) void k_big2(const float* __restrict__ st1,
                                                 const float* __restrict__ rho,
                                                 const float* __restrict__ w,
                                                 const unsigned short* __restrict__ cf16,
                                                 const unsigned short* __restrict__ Wt,
                                                 const float* __restrict__ bias,
                                                 float* __restrict__ c,
                                                 float* __restrict__ st2){
  __shared__ __align__(16) unsigned short ldsS[32*SP];
  __shared__ __align__(16) unsigned short ldsY[32*SP];
  int bx = blockIdx.x;
  int b = bx & 31, p = bx >> 5;
  int col = threadIdx.x;
  int t0 = 32*p;
  size_t cb = (size_t)b*NT*ND;
  int j0 = 2*p, j1 = 2*p + 1;

  float cfa[2][15];                    // held c' fine-row values (bf16-decoded)
  // ---------- phase A: one stash walk (dual extraction) + leaf blends + fine IDWT -> ldsS ----------
  {
    float x[64];
#pragma unroll
    for (int k = 0; k < 64; ++k) x[k] = st1[((size_t)b*64 + k)*ND + col];
    float pd[6], y0 = 0.f, y1 = 0.f;
    dwt_sel2<32>(x, j0>>1, pd[0], j0, y0, j1, y1);
    dwt_sel2<16>(x, j0>>2, pd[1], j0, y0, j1, y1);
    dwt_sel2< 8>(x, j0>>3, pd[2], j0, y0, j1, y1);
    dwt_sel2< 4>(x, j0>>4, pd[3], j0, y0, j1, y1);
    dwt_sel2< 2>(x, j0>>5, pd[4], j0, y0, j1, y1);
    dwt_sel2< 1>(x, j0>>6, pd[5], j0, y0, j1, y1);
    if (j0 == 0) y0 = x[0];

    // shared path rows (blend operands)
    float cpr[7];
    cpr[0] = rho[cb + col] * w[col];
#pragma unroll
    for (int l = 6; l >= 1; --l){
      int r = (64>>l) + (j0>>l);
      cpr[7-l] = rho[cb + (size_t)r*ND + col] * w[(size_t)r*ND + col];
    }
    // c' coarse rows j0, j1 (consumed by k_fin2)
    {
      float cv = rho[cb + (size_t)j0*ND + col] * w[(size_t)j0*ND + col];
      c[cb + (size_t)j0*ND + col] = cv - ETA*(cv - y0);
      float cw = rho[cb + (size_t)j1*ND + col] * w[(size_t)j1*ND + col];
      c[cb + (size_t)j1*ND + col] = cw - ETA*(cw - y1);
    }
    // blended coarse coeffs along the (shared) path
    float ncl[6];
#pragma unroll
    for (int l = 1; l <= 6; ++l){
      float cv = cpr[7-l];
      ncl[l-1] = cv - ETA*(cv - pd[l-1]);
    }
    float cvr = cpr[0];
    float apre = cvr - ETA*(cvr - x[0]);
#pragma unroll
    for (int l = 6; l >= 2; --l){
      float s = ((j0 >> (l-1)) & 1) ? -1.f : 1.f;
      apre = (apre + s*ncl[l-1]) * INVS;
    }
#pragma unroll
    for (int jj = 0; jj < 2; ++jj){
      int j = j0 + jj;
      float a = (apre + (jj ? -1.f : 1.f)*ncl[0]) * INVS;
      int fr[15]; fine_rows(j, fr);
      float f4, f3[2], f2a[4], f1[8];
      {
        float fv[15];
#pragma unroll
        for (int i = 0; i < 15; ++i){
          fv[i] = bf2f(cf16[cb + (size_t)fr[i]*ND + col]);
          cfa[jj][i] = fv[i];
        }
        f4 = fv[0];
#pragma unroll
        for (int i = 0; i < 2; ++i) f3[i]  = fv[1+i];
#pragma unroll
        for (int i = 0; i < 4; ++i) f2a[i] = fv[3+i];
#pragma unroll
        for (int i = 0; i < 8; ++i) f1[i]  = fv[7+i];
      }
      float A[16]; A[0] = a;
      idwtT<1>(A, &f4); idwtT<2>(A, f3); idwtT<4>(A, f2a); idwtT<8>(A, f1);
#pragma unroll
      for (int i = 0; i < 16; ++i) ldsS[(16*jj + i)*SP + col] = f2bf(A[i]);
    }
  }
  __syncthreads();
  // ---------- phase B: GEMM ----------
  {
    int wv = threadIdx.x >> 6, lane = threadIdx.x & 63;
    int row16 = lane & 15, kg = lane >> 4, n0 = wv*64;
    if (p > 0){
      int band = 32 - __clz(t0);
      gemm_tile_lds(ldsS, ldsY, Wt, bias, band, n0, row16, kg, 0, 32);
    } else {
#pragma unroll
      for (int bd = 0; bd < 6; ++bd){
        int lo = (bd==0) ? 0 : (1<<(bd-1));
        int hi = (bd==0) ? 1 : (1<<bd);
        gemm_tile_lds(ldsS, ldsY, Wt, bias, bd, n0, row16, kg, lo, hi);
      }
    }
  }
  __syncthreads();
  // ---------- phase C: final fine DWT, blend with held cfa, divide by w -> out; stash2 ----------
#pragma unroll
  for (int jj = 0; jj < 2; ++jj){
    int j = j0 + jj;
    float x[16];
#pragma unroll
    for (int i = 0; i < 16; ++i) x[i] = bf2f(ldsY[(16*jj + i)*SP + col]);
    float d1[8], d2v[4], d3[2], d4v;
    dwtT<8>(x, d1); dwtT<4>(x, d2v); dwtT<2>(x, d3); dwtT<1>(x, &d4v);
    st2[((size_t)b*64 + j)*ND + col] = x[0];
    int fr[15]; fine_rows(j, fr);
    float det[15];
    det[0] = d4v;
#pragma unroll
    for (int i = 0; i < 2; ++i) det[1+i] = d3[i];
#pragma unroll
    for (int i = 0; i < 4; ++i) det[3+i] = d2v[i];
#pragma unroll
    for (int i = 0; i < 8; ++i) det[7+i] = d1[i];
#pragma unroll
    for (int i = 0; i < 15; ++i){
      float cv = cfa[jj][i];
      float ww = w[(size_t)fr[i]*ND + col];
      c[cb + (size_t)fr[i]*ND + col] = (cv - ETA*(cv - det[i])) / ww;
    }
  }
}

// ---------------- k_fin2: out coarse row j from stash2 ----------------
__global__ __launch_bounds__(256, 4) void k_fin2(const float* __restrict__ st2,
                                                 const float* __restrict__ w,
                                                 float* __restrict__ c){
  int b = blockIdx.y, j = blockIdx.x, d = threadIdx.x;
  size_t cb = (size_t)b*NT*ND;

  float x[64];
#pragma unroll
  for (int k = 0; k < 64; ++k) x[k] = st2[((size_t)b*64 + k)*ND + d];

  float cj = c[cb + (size_t)j*ND + d];       // c' coarse row j (from k_big2)
  float wj = w[(size_t)j*ND + d];

  float yj = 0.f;
  dwt_sel<32>(x, j, yj);
  dwt_sel<16>(x, j, yj);
  dwt_sel< 8>(x, j, yj);
  dwt_sel< 4>(x, j, yj);
  dwt_sel< 2>(x, j, yj);
  dwt_sel< 1>(x, j, yj);
  if (j == 0) yj = x[0];

  c[cb + (size_t)j*ND + d] = (cj - ETA*(cj - yj)) / wj;
}

// ---------------- Wt[band][e][d] = bf16(W[band][d][e]) ----------------
__global__ __launch_bounds__(256) void k_wprep(const float* __restrict__ W,
                                               unsigned short* __restrict__ Wt){
  __shared__ float tbuf[32][33];
  int band = blockIdx.y;
  int tile = blockIdx.x;             // 0..63 -> 8x8 grid of 32x32 tiles
  int td0 = (tile >> 3) * 32, te0 = (tile & 7) * 32;
  int tx = threadIdx.x & 31, ty = threadIdx.x >> 5;
#pragma unroll
  for (int i = 0; i < 4; ++i){
    tbuf[ty*4 + i][tx] = W[(size_t)band*65536 + (size_t)(td0 + ty*4 + i)*256 + te0 + tx];
  }
  __syncthreads();
#pragma unroll
  for (int i = 0; i < 4; ++i){
    Wt[(size_t)band*65536 + (size_t)(te0 + ty*4 + i)*256 + td0 + tx] = f2bf(tbuf[tx][ty*4 + i]);
  }
}

extern "C" void kernel_launch(void* const* d_in, const int* in_sizes, int n_in,
                              void* d_out, int out_size, void* d_ws, size_t ws_size,
                              hipStream_t stream){
  const float* rho  = (const float*)d_in[0];
  const float* w    = (const float*)d_in[1];
  const float* W    = (const float*)d_in[2];
  const float* bias = (const float*)d_in[3];

  float* c = (float*)d_out;                                   // output buffer
  unsigned short* Wt = (unsigned short*)d_ws;                 // 1.44 MB bf16 transposed weights
  float* st1 = (float*)(Wt + (size_t)11 * 65536);             // 2 MB [b][64][256]
  float* st2 = st1 + (size_t)NB * 64 * ND;                    // 2 MB [b][64][256]
  unsigned short* cf16 = (unsigned short*)(st2 + (size_t)NB * 64 * ND);  // 16.8 MB bf16 c' fine rows

  k_wprep<<<dim3(64, 11), 256, 0, stream>>>(W, Wt);
  k_big1<<<NB*32, 256, 0, stream>>>(rho, w, Wt, bias, cf16, st1);
  k_big2<<<NB*32, 256, 0, stream>>>(st1, rho, w, cf16, Wt, bias, c, st2);
  k_fin2<<<dim3(64, NB), 256, 0, stream>>>(st2, w, c);
}

// Round 21
// 94.941 us; speedup vs baseline: 1.2235x; 1.0179x over previous
//
#include <hip/hip_runtime.h>
#include <hip/hip_bf16.h>

#define NB 32
#define NT 1024
#define ND 256
#define SP 264      // LDS tile pitch (bf16 elems): 528B rows, 16B-aligned
#define ETA 0.1f
#define INVS 0.70710678118654752440f

typedef short bf16x8 __attribute__((ext_vector_type(8)));
typedef float f32x4  __attribute__((ext_vector_type(4)));
typedef float f32x2  __attribute__((ext_vector_type(2)));

__device__ inline unsigned short f2bf(float f){
  __hip_bfloat16 h = __float2bfloat16(f);
  return *reinterpret_cast<unsigned short*>(&h);
}
__device__ inline float bf2f(unsigned short u){
  return __uint_as_float(((unsigned int)u) << 16);
}
__device__ inline f32x2 bfp2f(unsigned u){          // bf16 pair -> float2
  return (f32x2){ __uint_as_float(u << 16), __uint_as_float(u & 0xffff0000u) };
}
__device__ inline unsigned pack_bf2(f32x2 v){       // float2 -> bf16 pair (RNE)
  return ((unsigned)f2bf(v.y) << 16) | (unsigned)f2bf(v.x);
}

// ---- generic Haar ladders (compile-time indices) ----
template<int N, typename T>
__device__ inline void idwtT(T* a, const T* d){
#pragma unroll
  for (int i = N-1; i >= 0; --i){
    T av = a[i], dv = d[i];
    a[2*i]   = (av + dv) * INVS;
    a[2*i+1] = (av - dv) * INVS;
  }
}
template<int N, typename T>
__device__ inline void dwtT(T* a, T* d){
#pragma unroll
  for (int i = 0; i < N; ++i){
    T e = a[2*i], o = a[2*i+1];
    a[i] = (e + o) * INVS;
    d[i] = (e - o) * INVS;
  }
}
// coarse DWT level with shared path-detail + dual own-row extraction
template<int N>
__device__ inline void dwt_sel2(float* x, int pj, float& pdet,
                                int j0, float& y0, int j1, float& y1){
#pragma unroll
  for (int i = 0; i < N; ++i){
    float e = x[2*i], o = x[2*i+1];
    float aa = (e + o) * INVS, dd = (e - o) * INVS;
    x[i] = aa;
    if (i == pj)    pdet = dd;
    if (N + i == j0) y0 = dd;
    if (N + i == j1) y1 = dd;
  }
}
// single-extraction variant (k_fin2)
template<int N>
__device__ inline void dwt_sel(float* x, int j, float& yj){
#pragma unroll
  for (int i = 0; i < N; ++i){
    float e = x[2*i], o = x[2*i+1];
    float aa = (e + o) * INVS, dd = (e - o) * INVS;
    x[i] = aa;
    if (N + i == j) yj = dd;
  }
}

__device__ inline void fine_rows(int j, int* fr){
  fr[0] = 64 + j;
#pragma unroll
  for (int i = 0; i < 2; ++i) fr[1+i] = 128 + 2*j + i;
#pragma unroll
  for (int i = 0; i < 4; ++i) fr[3+i] = 256 + 4*j + i;
#pragma unroll
  for (int i = 0; i < 8; ++i) fr[7+i] = 512 + 8*j + i;
}

// ---- GEMM phase: one wave computes M32 x N64 for given band, A from ldsS, Y -> ldsY ----
__device__ inline void gemm_tile_lds(const unsigned short* ldsS,
                                     unsigned short* ldsY,
                                     const unsigned short* __restrict__ Wt,
                                     const float* __restrict__ bias,
                                     int band, int n0, int row16, int kg,
                                     int lo, int hi){
  const unsigned short* Wb = Wt + (size_t)band * 65536;
  bf16x8 breg[8][4];
#pragma unroll
  for (int kk = 0; kk < 8; ++kk)
#pragma unroll
    for (int ni = 0; ni < 4; ++ni)
      breg[kk][ni] = *(const bf16x8*)(Wb + (size_t)(n0 + 16*ni + row16)*256 + kk*32 + kg*8);
  float bv[4];
#pragma unroll
  for (int ni = 0; ni < 4; ++ni) bv[ni] = bias[band*256 + n0 + 16*ni + row16];

  f32x4 acc[2][4];
#pragma unroll
  for (int mi = 0; mi < 2; ++mi)
#pragma unroll
    for (int ni = 0; ni < 4; ++ni) acc[mi][ni] = (f32x4){0.f,0.f,0.f,0.f};

#pragma unroll
  for (int kk = 0; kk < 8; ++kk){
    bf16x8 a0 = *(const bf16x8*)&ldsS[row16*SP + kk*32 + kg*8];
    bf16x8 a1 = *(const bf16x8*)&ldsS[(16 + row16)*SP + kk*32 + kg*8];
#pragma unroll
    for (int ni = 0; ni < 4; ++ni){
      acc[0][ni] = __builtin_amdgcn_mfma_f32_16x16x32_bf16(a0, breg[kk][ni], acc[0][ni], 0,0,0);
      acc[1][ni] = __builtin_amdgcn_mfma_f32_16x16x32_bf16(a1, breg[kk][ni], acc[1][ni], 0,0,0);
    }
  }
#pragma unroll
  for (int ni = 0; ni < 4; ++ni)
#pragma unroll
    for (int mi = 0; mi < 2; ++mi)
#pragma unroll
      for (int jj = 0; jj < 4; ++jj){
        int trow = 16*mi + kg*4 + jj;   // C/D: row=(lane>>4)*4+reg, col=lane&15
        if (trow >= lo && trow < hi)
          ldsY[trow*SP + n0 + 16*ni + row16] = f2bf(acc[mi][ni][jj] + bv[ni]);
      }
}

// ================ BIG1 (vectorized f32x2 loads): IDWT(w*rho) -> GEMM -> fine DWT + blend ================
// thread (jj = tid>>7, cp = tid&127): ONE chunk j=2p+jj, TWO columns 2cp..2cp+1
__global__ __launch_bounds__(256, 2) void k_big1(const float* __restrict__ rho,
                                                 const float* __restrict__ w,
                                                 const unsigned short* __restrict__ Wt,
                                                 const float* __restrict__ bias,
                                                 unsigned short* __restrict__ cf16,
                                                 float* __restrict__ st1){
  __shared__ __align__(16) unsigned short ldsS[32*SP];
  __shared__ __align__(16) unsigned short ldsY[32*SP];
  int bx = blockIdx.x;
  int b = bx & 31, p = bx >> 5;        // p=0: masked rows 0..31; p>=1: rows 32p..32p+31
  int tid = threadIdx.x;
  int jj = tid >> 7, cp = tid & 127;
  int col2 = cp * 2;
  int j = 2*p + jj;
  int t0 = 32*p;
  size_t cb = (size_t)b*NT*ND;

  f32x2 cva[15];                       // held w*rho fine-row products (2 cols)
  // ---------- phase A: chunk IDWT (f32x2) -> ldsS ----------
  {
    int crow[7]; crow[0] = 0;
#pragma unroll
    for (int l = 6; l >= 1; --l) crow[7-l] = (64>>l) + (j>>l);
    f32x2 cpr[7];
#pragma unroll
    for (int i = 0; i < 7; ++i){
      f32x2 rv = *(const f32x2*)(rho + cb + (size_t)crow[i]*ND + col2);
      f32x2 wv = *(const f32x2*)(w + (size_t)crow[i]*ND + col2);
      cpr[i] = rv * wv;
    }
    int fr[15]; fine_rows(j, fr);
#pragma unroll
    for (int i = 0; i < 15; ++i){
      f32x2 rv = *(const f32x2*)(rho + cb + (size_t)fr[i]*ND + col2);
      f32x2 wv = *(const f32x2*)(w + (size_t)fr[i]*ND + col2);
      cva[i] = rv * wv;
    }
    f32x2 a = cpr[0];
#pragma unroll
    for (int l = 6; l >= 1; --l){
      float s = ((j >> (l-1)) & 1) ? -INVS : INVS;
      a = a*INVS + cpr[7-l]*s;
    }
    f32x2 f4 = cva[0];
    f32x2 f3[2], f2a[4], f1[8];
#pragma unroll
    for (int i = 0; i < 2; ++i) f3[i]  = cva[1+i];
#pragma unroll
    for (int i = 0; i < 4; ++i) f2a[i] = cva[3+i];
#pragma unroll
    for (int i = 0; i < 8; ++i) f1[i]  = cva[7+i];
    f32x2 A[16]; A[0] = a;
    idwtT<1>(A, &f4); idwtT<2>(A, f3); idwtT<4>(A, f2a); idwtT<8>(A, f1);
#pragma unroll
    for (int i = 0; i < 16; ++i)
      *(unsigned*)&ldsS[(16*jj + i)*SP + col2] = pack_bf2(A[i]);
  }
  __syncthreads();
  // ---------- phase B: GEMM (unchanged wave mapping) ----------
  {
    int wv = threadIdx.x >> 6, lane = threadIdx.x & 63;
    int row16 = lane & 15, kg = lane >> 4, n0 = wv*64;
    if (p > 0){
      int band = 32 - __clz(t0);
      gemm_tile_lds(ldsS, ldsY, Wt, bias, band, n0, row16, kg, 0, 32);
    } else {
#pragma unroll
      for (int bd = 0; bd < 6; ++bd){
        int lo = (bd==0) ? 0 : (1<<(bd-1));
        int hi = (bd==0) ? 1 : (1<<bd);
        gemm_tile_lds(ldsS, ldsY, Wt, bias, bd, n0, row16, kg, lo, hi);
      }
    }
  }
  __syncthreads();
  // ---------- phase C: fine DWT (f32x2) of Y-tile, blend with held cva, write cf16 + st1 ----------
  {
    f32x2 x[16];
#pragma unroll
    for (int i = 0; i < 16; ++i)
      x[i] = bfp2f(*(const unsigned*)&ldsY[(16*jj + i)*SP + col2]);
    f32x2 d1[8], d2v[4], d3[2], d4v;
    dwtT<8>(x, d1); dwtT<4>(x, d2v); dwtT<2>(x, d3); dwtT<1>(x, &d4v);
    *(f32x2*)(st1 + ((size_t)b*64 + j)*ND + col2) = x[0];
    int fr[15]; fine_rows(j, fr);
    f32x2 det[15];
    det[0] = d4v;
#pragma unroll
    for (int i = 0; i < 2; ++i) det[1+i] = d3[i];
#pragma unroll
    for (int i = 0; i < 4; ++i) det[3+i] = d2v[i];
#pragma unroll
    for (int i = 0; i < 8; ++i) det[7+i] = d1[i];
#pragma unroll
    for (int i = 0; i < 15; ++i){
      f32x2 cv = cva[i];
      f32x2 nc = cv - (cv - det[i])*ETA;
      *(unsigned*)(cf16 + cb + (size_t)fr[i]*ND + col2) = pack_bf2(nc);
    }
  }
}

// ============ BIG2: coarse walk + IDWT(c') -> GEMM -> final DWT/blend/div -> c, st2 ============
__global__ __launch_bounds__(256, 2) void k_big2(const float* __restrict__ st1,
                                                 const float* __restrict__ rho,
                                                 const float* __restrict__ w,
                                                 const unsigned short* __restrict__ cf16,
                                                 const unsigned short* __restrict__ Wt,
                                                 const float* __restrict__ bias,
                                                 float* __restrict__ c,
                                                 float* __restrict__ st2){
  __shared__ __align__(16) unsigned short ldsS[32*SP];
  __shared__ __align__(16) unsigned short ldsY[32*SP];
  int bx = blockIdx.x;
  int b = bx & 31, p = bx >> 5;
  int col = threadIdx.x;
  int t0 = 32*p;
  size_t cb = (size_t)b*NT*ND;
  int j0 = 2*p, j1 = 2*p + 1;

  float cfa[2][15];                    // held c' fine-row values (bf16-decoded)
  // ---------- phase A: one stash walk (dual extraction) + leaf blends + fine IDWT -> ldsS ----------
  {
    float x[64];
#pragma unroll
    for (int k = 0; k < 64; ++k) x[k] = st1[((size_t)b*64 + k)*ND + col];
    float pd[6], y0 = 0.f, y1 = 0.f;
    dwt_sel2<32>(x, j0>>1, pd[0], j0, y0, j1, y1);
    dwt_sel2<16>(x, j0>>2, pd[1], j0, y0, j1, y1);
    dwt_sel2< 8>(x, j0>>3, pd[2], j0, y0, j1, y1);
    dwt_sel2< 4>(x, j0>>4, pd[3], j0, y0, j1, y1);
    dwt_sel2< 2>(x, j0>>5, pd[4], j0, y0, j1, y1);
    dwt_sel2< 1>(x, j0>>6, pd[5], j0, y0, j1, y1);
    if (j0 == 0) y0 = x[0];

    // shared path rows (blend operands)
    float cpr[7];
    cpr[0] = rho[cb + col] * w[col];
#pragma unroll
    for (int l = 6; l >= 1; --l){
      int r = (64>>l) + (j0>>l);
      cpr[7-l] = rho[cb + (size_t)r*ND + col] * w[(size_t)r*ND + col];
    }
    // c' coarse rows j0, j1 (consumed by k_fin2)
    {
      float cv = rho[cb + (size_t)j0*ND + col] * w[(size_t)j0*ND + col];
      c[cb + (size_t)j0*ND + col] = cv - ETA*(cv - y0);
      float cw = rho[cb + (size_t)j1*ND + col] * w[(size_t)j1*ND + col];
      c[cb + (size_t)j1*ND + col] = cw - ETA*(cw - y1);
    }
    // blended coarse coeffs along the (shared) path
    float ncl[6];
#pragma unroll
    for (int l = 1; l <= 6; ++l){
      float cv = cpr[7-l];
      ncl[l-1] = cv - ETA*(cv - pd[l-1]);
    }
    float cvr = cpr[0];
    float apre = cvr - ETA*(cvr - x[0]);
#pragma unroll
    for (int l = 6; l >= 2; --l){
      float s = ((j0 >> (l-1)) & 1) ? -1.f : 1.f;
      apre = (apre + s*ncl[l-1]) * INVS;
    }
#pragma unroll
    for (int jj = 0; jj < 2; ++jj){
      int j = j0 + jj;
      float a = (apre + (jj ? -1.f : 1.f)*ncl[0]) * INVS;
      int fr[15]; fine_rows(j, fr);
      float f4, f3[2], f2a[4], f1[8];
      {
        float fv[15];
#pragma unroll
        for (int i = 0; i < 15; ++i){
          fv[i] = bf2f(cf16[cb + (size_t)fr[i]*ND + col]);
          cfa[jj][i] = fv[i];
        }
        f4 = fv[0];
#pragma unroll
        for (int i = 0; i < 2; ++i) f3[i]  = fv[1+i];
#pragma unroll
        for (int i = 0; i < 4; ++i) f2a[i] = fv[3+i];
#pragma unroll
        for (int i = 0; i < 8; ++i) f1[i]  = fv[7+i];
      }
      float A[16]; A[0] = a;
      idwtT<1>(A, &f4); idwtT<2>(A, f3); idwtT<4>(A, f2a); idwtT<8>(A, f1);
#pragma unroll
      for (int i = 0; i < 16; ++i) ldsS[(16*jj + i)*SP + col] = f2bf(A[i]);
    }
  }
  __syncthreads();
  // ---------- phase B: GEMM ----------
  {
    int wv = threadIdx.x >> 6, lane = threadIdx.x & 63;
    int row16 = lane & 15, kg = lane >> 4, n0 = wv*64;
    if (p > 0){
      int band = 32 - __clz(t0);
      gemm_tile_lds(ldsS, ldsY, Wt, bias, band, n0, row16, kg, 0, 32);
    } else {
#pragma unroll
      for (int bd = 0; bd < 6; ++bd){
        int lo = (bd==0) ? 0 : (1<<(bd-1));
        int hi = (bd==0) ? 1 : (1<<bd);
        gemm_tile_lds(ldsS, ldsY, Wt, bias, bd, n0, row16, kg, lo, hi);
      }
    }
  }
  __syncthreads();
  // ---------- phase C: final fine DWT, blend with held cfa, divide by w -> out; stash2 ----------
#pragma unroll
  for (int jj = 0; jj < 2; ++jj){
    int j = j0 + jj;
    float x[16];
#pragma unroll
    for (int i = 0; i < 16; ++i) x[i] = bf2f(ldsY[(16*jj + i)*SP + col]);
    float d1[8], d2v[4], d3[2], d4v;
    dwtT<8>(x, d1); dwtT<4>(x, d2v); dwtT<2>(x, d3); dwtT<1>(x, &d4v);
    st2[((size_t)b*64 + j)*ND + col] = x[0];
    int fr[15]; fine_rows(j, fr);
    float det[15];
    det[0] = d4v;
#pragma unroll
    for (int i = 0; i < 2; ++i) det[1+i] = d3[i];
#pragma unroll
    for (int i = 0; i < 4; ++i) det[3+i] = d2v[i];
#pragma unroll
    for (int i = 0; i < 8; ++i) det[7+i] = d1[i];
#pragma unroll
    for (int i = 0; i < 15; ++i){
      float cv = cfa[jj][i];
      float ww = w[(size_t)fr[i]*ND + col];
      c[cb + (size_t)fr[i]*ND + col] = (cv - ETA*(cv - det[i])) / ww;
    }
  }
}

// ---------------- k_fin2: out coarse row j from stash2 ----------------
__global__ __launch_bounds__(256, 4) void k_fin2(const float* __restrict__ st2,
                                                 const float* __restrict__ w,
                                                 float* __restrict__ c){
  int b = blockIdx.y, j = blockIdx.x, d = threadIdx.x;
  size_t cb = (size_t)b*NT*ND;

  float x[64];
#pragma unroll
  for (int k = 0; k < 64; ++k) x[k] = st2[((size_t)b*64 + k)*ND + d];

  float cj = c[cb + (size_t)j*ND + d];       // c' coarse row j (from k_big2)
  float wj = w[(size_t)j*ND + d];

  float yj = 0.f;
  dwt_sel<32>(x, j, yj);
  dwt_sel<16>(x, j, yj);
  dwt_sel< 8>(x, j, yj);
  dwt_sel< 4>(x, j, yj);
  dwt_sel< 2>(x, j, yj);
  dwt_sel< 1>(x, j, yj);
  if (j == 0) yj = x[0];

  c[cb + (size_t)j*ND + d] = (cj - ETA*(cj - yj)) / wj;
}

// ---------------- Wt[band][e][d] = bf16(W[band][d][e]) ----------------
__global__ __launch_bounds__(256) void k_wprep(const float* __restrict__ W,
                                               unsigned short* __restrict__ Wt){
  __shared__ float tbuf[32][33];
  int band = blockIdx.y;
  int tile = blockIdx.x;             // 0..63 -> 8x8 grid of 32x32 tiles
  int td0 = (tile >> 3) * 32, te0 = (tile & 7) * 32;
  int tx = threadIdx.x & 31, ty = threadIdx.x >> 5;
#pragma unroll
  for (int i = 0; i < 4; ++i){
    tbuf[ty*4 + i][tx] = W[(size_t)band*65536 + (size_t)(td0 + ty*4 + i)*256 + te0 + tx];
  }
  __syncthreads();
#pragma unroll
  for (int i = 0; i < 4; ++i){
    Wt[(size_t)band*65536 + (size_t)(te0 + ty*4 + i)*256 + td0 + tx] = f2bf(tbuf[tx][ty*4 + i]);
  }
}

extern "C" void kernel_launch(void* const* d_in, const int* in_sizes, int n_in,
                              void* d_out, int out_size, void* d_ws, size_t ws_size,
                              hipStream_t stream){
  const float* rho  = (const float*)d_in[0];
  const float* w    = (const float*)d_in[1];
  const float* W    = (const float*)d_in[2];
  const float* bias = (const float*)d_in[3];

  float* c = (float*)d_out;                                   // output buffer
  unsigned short* Wt = (unsigned short*)d_ws;                 // 1.44 MB bf16 transposed weights
  float* st1 = (float*)(Wt + (size_t)11 * 65536);             // 2 MB [b][64][256]
  float* st2 = st1 + (size_t)NB * 64 * ND;                    // 2 MB [b][64][256]
  unsigned short* cf16 = (unsigned short*)(st2 + (size_t)NB * 64 * ND);  // 16.8 MB bf16 c' fine rows

  k_wprep<<<dim3(64, 11), 256, 0, stream>>>(W, Wt);
  k_big1<<<NB*32, 256, 0, stream>>>(rho, w, Wt, bias, cf16, st1);
  k_big2<<<NB*32, 256, 0, stream>>>(st1, rho, w, cf16, Wt, bias, c, st2);
  k_fin2<<<dim3(64, NB), 256, 0, stream>>>(st2, w, c);
}